// Round 7
// baseline (97.533 us; speedup 1.0000x reference)
//
#include <hip/hip_runtime.h>
#include <stdint.h>

// Segmented kNN graph: M=65536 pts, D=16, 64 segments x 1024 pts, K=16.
// Output: int32 src[M*16] then int32 dst[M*16].
//
// v7 = v6 arithmetic, restructured for concurrency. Evidence (r5/r6): very
// different inner-op counts give identical 43us -> latency-bound at 16
// waves/CU, not issue- or LDS-bound. Fix: 512-thread blocks (8 waves) over
// the same 38.9KB LDS -> 4 blocks/CU = 32 waves/CU (100% thread slots).
// Each wave: 16 queries x 512 cands (8 batches); halves merged across waves
// w <-> w^4 via LDS (frag buffer reused after barrier).
//  - fragment-ready LDS layout: 2 contiguous ds_read_b128 per batch.
//  - coords stored scaled by -2 (exact in f16); norms+128 as MFMA C operand;
//    key pack = 1 v_and_or per key; raw float bits order-preserving (kf>0).
//  - Batcher sort-16 (63 CE) + bitonic merges.

#define L_SEG 1024
#define M_PTS 65536

typedef __fp16 fp16x2 __attribute__((ext_vector_type(2)));
typedef __fp16 fp16x4 __attribute__((ext_vector_type(4)));
typedef float  f32x4  __attribute__((ext_vector_type(4)));

__device__ __forceinline__ uint32_t umn(uint32_t a, uint32_t b) { return a < b ? a : b; }
__device__ __forceinline__ uint32_t umx(uint32_t a, uint32_t b) { return a > b ? a : b; }

// bitonic clean of 16 (input bitonic, output sorted ascending): 32 CEs
__device__ __forceinline__ void clean16(uint32_t* A) {
    #pragma unroll
    for (int j = 8; j > 0; j >>= 1) {
        #pragma unroll
        for (int i = 0; i < 16; ++i) {
            int p = i ^ j;
            if (p > i) {
                uint32_t lo = umn(A[i], A[p]);
                uint32_t hi = umx(A[i], A[p]);
                A[i] = lo; A[p] = hi;
            }
        }
    }
}

__global__ __launch_bounds__(512, 8) void knn_v7_kernel(const float* __restrict__ x,
                                                        int* __restrict__ out) {
    // sfrag: 16 batches x 2KB. byte(bat,tt,g,col) =
    //   bat*2048 + (tt>>1)*1024 + (g*16+col)*16 + (tt&1)*8
    __shared__ __attribute__((aligned(16))) __fp16 sfrag[16384];  // 32 KB, -2*c (f16)
    __shared__ __attribute__((aligned(16))) float  ssq[L_SEG];    // |c|^2 + 128 (f32)
    __shared__ __attribute__((aligned(16))) __fp16 sq16[64 * 16]; // block's 64 queries, f16

    const int tid = threadIdx.x;
    const int b   = blockIdx.x;
    // bijective: seg = lo*8+hi (lo=b&7 ~ XCD id -> one XCD covers 8 segs)
    const int seg = (b & 7) * 8 + (b >> 7);
    const int qp  = (b >> 3) & 15;
    const float* xseg = x + (size_t)seg * (L_SEG * 16);
    const f32x4* gx4  = (const f32x4*)xseg;

    // ---- stage A-frags: coords * -2, fragment-ready layout (512 thr, 8 iters) ----
    {
        fp16x4* fr = (fp16x4*)sfrag;  // 8-B entries, entry index F -> byte F*8
        #pragma unroll
        for (int i = 0; i < 8; ++i) {
            const int F    = i * 512 + tid;
            const int bat  = F >> 8;
            const int hlf  = (F >> 7) & 1;
            const int e    = (F >> 1) & 63;
            const int lo   = F & 1;
            const int tt   = hlf * 2 + lo;
            const int gg   = e >> 4;
            const int cc   = e & 15;
            const int cand = bat * 64 + tt * 16 + cc;
            f32x4 v = gx4[cand * 4 + gg];
            union { fp16x2 h2[2]; fp16x4 h4; } u;
            u.h2[0] = __builtin_amdgcn_cvt_pkrtz(-2.0f * v[0], -2.0f * v[1]);
            u.h2[1] = __builtin_amdgcn_cvt_pkrtz(-2.0f * v[2], -2.0f * v[3]);
            fr[F] = u.h4;
        }
    }
    // ---- stage biased norms (f32, from global): 2 cands per thread ----
    {
        const int c0 = tid << 1;
        #pragma unroll
        for (int c = 0; c < 2; ++c) {
            float s = 128.0f;
            #pragma unroll
            for (int d = 0; d < 4; ++d) {
                f32x4 v = gx4[(c0 + c) * 4 + d];
                s = __builtin_fmaf(v[0], v[0], s);
                s = __builtin_fmaf(v[1], v[1], s);
                s = __builtin_fmaf(v[2], v[2], s);
                s = __builtin_fmaf(v[3], v[3], s);
            }
            ssq[c0 + c] = s;
        }
    }
    // ---- stage this block's 64 queries (unscaled f16) ----
    if (tid < 64) {
        const f32x4* qg = gx4 + (size_t)(qp * 64 + tid) * 4;
        fp16x4* dst = (fp16x4*)(sq16 + (size_t)tid * 16);
        #pragma unroll
        for (int d = 0; d < 4; ++d) {
            f32x4 v = qg[d];
            union { fp16x2 h2[2]; fp16x4 h4; } u;
            u.h2[0] = __builtin_amdgcn_cvt_pkrtz(v[0], v[1]);
            u.h2[1] = __builtin_amdgcn_cvt_pkrtz(v[2], v[3]);
            dst[d] = u.h4;
        }
    }
    __syncthreads();

    const int lane = tid & 63;
    const int w    = tid >> 6;    // 0..7
    const int qsub = w & 3;       // query group of 16 within block
    const int half = w >> 2;      // candidate half (0..1)
    const int g    = lane >> 4;   // candidate-row group
    const int col  = lane & 15;   // this lane's query column
    const int qloc = qp * 64 + qsub * 16 + col;

    // B fragment: query (qsub*16+col), dims 4g..4g+3, unscaled
    const fp16x4 bfrag = *(const fp16x4*)(sq16 + (size_t)(qsub * 16 + col) * 16 + g * 4);

    uint32_t A[16];
    #pragma unroll
    for (int i = 0; i < 16; ++i) A[i] = 0xFFFFFFFFu;

    const char* fb = (const char*)sfrag;
    const int   lb = lane * 16;

    union F2H { f32x4 v; fp16x4 h[2]; };

    #pragma unroll 2
    for (int t0 = 0; t0 < 8; ++t0) {
        const int bat = half * 8 + t0;
        F2H c01, c23;
        c01.v = *(const f32x4*)(fb + bat * 2048 + lb);
        c23.v = *(const f32x4*)(fb + bat * 2048 + 1024 + lb);

        uint32_t B[16];
        #pragma unroll
        for (int tt = 0; tt < 4; ++tt) {
            const int tb = bat * 64 + tt * 16;
            const f32x4 sq = *(const f32x4*)&ssq[tb + g * 4];
            fp16x4 af = (tt < 2) ? c01.h[tt] : c23.h[tt - 2];
            // acc[v] = |c|^2 + 128 - 2*<c,q>  (C operand carries norm+bias)
            f32x4 acc = __builtin_amdgcn_mfma_f32_16x16x16f16(af, bfrag, sq, 0, 0, 0);
            const uint32_t idxt = (uint32_t)(tb + g * 4);
            #pragma unroll
            for (int v = 0; v < 4; ++v)
                B[tt * 4 + v] = (__float_as_uint(acc[v]) & 0xFFFFFC00u) | (idxt + (uint32_t)v);
        }
        // Batcher odd-even mergesort-16, ascending (63 CEs)
        #pragma unroll
        for (int p = 1; p < 16; p <<= 1) {
            #pragma unroll
            for (int k = p; k >= 1; k >>= 1) {
                #pragma unroll
                for (int j = (k & (p - 1)); j + k < 16; j += 2 * k) {
                    #pragma unroll
                    for (int i = 0; i <= ((k - 1 < 15 - j - k) ? k - 1 : 15 - j - k); ++i) {
                        if ((i + j) / (2 * p) == (i + j + k) / (2 * p)) {
                            uint32_t lo = umn(B[i + j], B[i + j + k]);
                            uint32_t hi = umx(B[i + j], B[i + j + k]);
                            B[i + j] = lo; B[i + j + k] = hi;
                        }
                    }
                }
            }
        }
        // merge sorted B into sorted A, keep lowest 16
        #pragma unroll
        for (int i = 0; i < 16; ++i) A[i] = umn(A[i], B[15 - i]);
        clean16(A);
    }

    // in-wave merges: lanes xor 16, 32 (same query, disjoint candidate rows)
    #pragma unroll
    for (int m = 16; m <= 32; m <<= 1) {
        uint32_t P[16];
        #pragma unroll
        for (int i = 0; i < 16; ++i) P[i] = (uint32_t)__shfl_xor((int)A[15 - i], m, 64);
        #pragma unroll
        for (int i = 0; i < 16; ++i) A[i] = umn(A[i], P[i]);
        clean16(A);
    }

    // ---- cross-wave (candidate-half) merge via LDS: w <-> w^4 ----
    __syncthreads();  // all waves done reading sfrag; reuse as merge buffer
    uint32_t (*smerge)[17] = (uint32_t (*)[17])sfrag;
    const int qb = qsub * 16 + col;  // block-local query 0..63
    if (half == 1) {
        #pragma unroll
        for (int v = 0; v < 4; ++v) smerge[qb][g * 4 + v] = A[g * 4 + v];
    }
    __syncthreads();
    if (half == 0) {
        uint32_t P[16];
        #pragma unroll
        for (int i = 0; i < 16; ++i) P[i] = smerge[qb][15 - i];
        #pragma unroll
        for (int i = 0; i < 16; ++i) A[i] = umn(A[i], P[i]);
        clean16(A);

        // Epilogue: lane (g,col) writes int4 #g of src and dst for its query.
        const int base = seg * L_SEG;
        const int q    = base + qloc;
        uint32_t r[4];
        #pragma unroll
        for (int v = 0; v < 4; ++v) {  // static select of A[4g+v]
            uint32_t t01 = (g & 1) ? A[4 + v]  : A[v];
            uint32_t t23 = (g & 1) ? A[12 + v] : A[8 + v];
            r[v] = (g & 2) ? t23 : t01;
        }
        int4 sv;
        sv.x = base + (int)(r[0] & 1023u);
        sv.y = base + (int)(r[1] & 1023u);
        sv.z = base + (int)(r[2] & 1023u);
        sv.w = base + (int)(r[3] & 1023u);
        ((int4*)out)[(size_t)q * 4 + g] = sv;
        ((int4*)out)[(size_t)M_PTS * 4 + (size_t)q * 4 + g] = make_int4(q, q, q, q);
    }
}

extern "C" void kernel_launch(void* const* d_in, const int* in_sizes, int n_in,
                              void* d_out, int out_size, void* d_ws, size_t ws_size,
                              hipStream_t stream) {
    const float* x = (const float*)d_in[0];
    // d_in[1] = segs (int64, all 1024) — static per problem setup, unused.
    int* out = (int*)d_out;
    (void)d_ws; (void)ws_size;
    knn_v7_kernel<<<dim3(1024), dim3(512), 0, stream>>>(x, out);
}

// Round 8
// 86.628 us; speedup vs baseline: 1.1259x; 1.1259x over previous
//
#include <hip/hip_runtime.h>
#include <stdint.h>

// Segmented kNN graph: M=65536 pts, D=16, 64 segments x 1024 pts, K=16.
// Output: int32 src[M*16] then int32 dst[M*16].
//
// v8 = v6 arithmetic + EXACT pair-min pre-reduction (halves sort work).
// Evidence r5-r7: time tracks total VALU count (43-46us across occupancy/
// conflict variants, VALUBusy ~60%) -> cut ops/key algorithmically.
// Pairs (2p,2p+1): keep min; true top-16 subset of {top-16 pairs} x
// {winner,partner} (if x in top16, <=15 pairmins < x's own) -> end repair
// recomputes 16 partner dists (v_dot2_f32_f16) and merges dup-free.
// Keys: f32 bits of (|c|^2+128-2<c,q>) | 10-bit idx (order-preserving).
// MFMA 16x16x16f16, C operand = norms. launch_bounds(256,4): no spill
// (v7's (512,8) forced VGPR=32 -> scratch, WRITE 24->41MB).

#define L_SEG 1024
#define M_PTS 65536

typedef __fp16 fp16x2 __attribute__((ext_vector_type(2)));
typedef __fp16 fp16x4 __attribute__((ext_vector_type(4)));
typedef float  f32x4  __attribute__((ext_vector_type(4)));

__device__ __forceinline__ uint32_t umn(uint32_t a, uint32_t b) { return a < b ? a : b; }
__device__ __forceinline__ uint32_t umx(uint32_t a, uint32_t b) { return a > b ? a : b; }

#define CE(arr, i, p) { uint32_t lo = umn(arr[i], arr[p]); uint32_t hi = umx(arr[i], arr[p]); arr[i] = lo; arr[p] = hi; }

// bitonic clean of 16 (input bitonic, output sorted ascending): 32 CEs
__device__ __forceinline__ void clean16(uint32_t* A) {
    #pragma unroll
    for (int j = 8; j > 0; j >>= 1) {
        #pragma unroll
        for (int i = 0; i < 16; ++i) {
            int p = i ^ j;
            if (p > i) CE(A, i, p);
        }
    }
}

// Batcher odd-even mergesort-16, ascending (63 CEs)
__device__ __forceinline__ void sort16(uint32_t* B) {
    #pragma unroll
    for (int p = 1; p < 16; p <<= 1) {
        #pragma unroll
        for (int k = p; k >= 1; k >>= 1) {
            #pragma unroll
            for (int j = (k & (p - 1)); j + k < 16; j += 2 * k) {
                #pragma unroll
                for (int i = 0; i <= ((k - 1 < 15 - j - k) ? k - 1 : 15 - j - k); ++i) {
                    if ((i + j) / (2 * p) == (i + j + k) / (2 * p)) CE(B, i + j, i + j + k);
                }
            }
        }
    }
}

// cross-lane merges over g (xor 16 then 32): disjoint contents per lane
__device__ __forceinline__ void mergeg(uint32_t* A) {
    #pragma unroll
    for (int m = 16; m <= 32; m <<= 1) {
        uint32_t P[16];
        #pragma unroll
        for (int i = 0; i < 16; ++i) P[i] = (uint32_t)__shfl_xor((int)A[15 - i], m, 64);
        #pragma unroll
        for (int i = 0; i < 16; ++i) A[i] = umn(A[i], P[i]);
        clean16(A);
    }
}

__device__ __forceinline__ uint32_t sel4(const uint32_t* A, int g, int v) {
    uint32_t t01 = (g & 1) ? A[4 + v]  : A[v];
    uint32_t t23 = (g & 1) ? A[12 + v] : A[8 + v];
    return (g & 2) ? t23 : t01;
}

__global__ __launch_bounds__(256, 4) void knn_v8_kernel(const float* __restrict__ x,
                                                        int* __restrict__ out) {
    __shared__ __attribute__((aligned(16))) __fp16 sc[L_SEG * 16];  // -2*c, [cand][dim], 32KB
    __shared__ __attribute__((aligned(16))) float  ssq[L_SEG];      // |c|^2 + 128 (f32)
    __shared__ __attribute__((aligned(16))) __fp16 sq16[64 * 16];   // block's queries, f16

    const int tid = threadIdx.x;
    const int b   = blockIdx.x;
    const int seg = (b & 7) * 8 + (b >> 7);  // XCD swizzle, bijective
    const int qp  = (b >> 3) & 15;
    const float* xseg = x + (size_t)seg * (L_SEG * 16);
    const f32x4* gx4  = (const f32x4*)xseg;

    // ---- stage coords * -2 as f16, plain [cand][dim] layout ----
    {
        fp16x4* scv = (fp16x4*)sc;
        #pragma unroll
        for (int i = 0; i < 16; ++i) {
            f32x4 v = gx4[tid + 256 * i];
            union { fp16x2 h2[2]; fp16x4 h4; } u;
            u.h2[0] = __builtin_amdgcn_cvt_pkrtz(-2.0f * v[0], -2.0f * v[1]);
            u.h2[1] = __builtin_amdgcn_cvt_pkrtz(-2.0f * v[2], -2.0f * v[3]);
            scv[tid + 256 * i] = u.h4;
        }
    }
    // ---- stage biased norms (f32 from global) ----
    {
        const int c0 = tid << 2;
        #pragma unroll
        for (int c = 0; c < 4; ++c) {
            float s = 128.0f;
            #pragma unroll
            for (int d = 0; d < 4; ++d) {
                f32x4 v = gx4[(c0 + c) * 4 + d];
                s = __builtin_fmaf(v[0], v[0], s);
                s = __builtin_fmaf(v[1], v[1], s);
                s = __builtin_fmaf(v[2], v[2], s);
                s = __builtin_fmaf(v[3], v[3], s);
            }
            ssq[c0 + c] = s;
        }
    }
    // ---- stage this block's 64 queries (unscaled f16) ----
    if (tid < 64) {
        const f32x4* qg = gx4 + (size_t)(qp * 64 + tid) * 4;
        fp16x4* dst = (fp16x4*)(sq16 + (size_t)tid * 16);
        #pragma unroll
        for (int d = 0; d < 4; ++d) {
            f32x4 v = qg[d];
            union { fp16x2 h2[2]; fp16x4 h4; } u;
            u.h2[0] = __builtin_amdgcn_cvt_pkrtz(v[0], v[1]);
            u.h2[1] = __builtin_amdgcn_cvt_pkrtz(v[2], v[3]);
            dst[d] = u.h4;
        }
    }
    __syncthreads();

    const int lane = tid & 63;
    const int w    = tid >> 6;
    const int g    = lane >> 4;   // candidate-row group (lane owns cands 4g..4g+3 per tile)
    const int col  = lane & 15;   // query column
    const int qloc = qp * 64 + w * 16 + col;

    const fp16x4 bfrag = *(const fp16x4*)(sq16 + (size_t)(w * 16 + col) * 16 + g * 4);

    uint32_t A[16];
    #pragma unroll
    for (int i = 0; i < 16; ++i) A[i] = 0xFFFFFFFFu;

    const __fp16* ap  = sc + (size_t)col * 16 + g * 4;   // A-frag base (v5 layout)
    const float*  sqp = ssq + g * 4;
    const uint32_t vg4 = (uint32_t)(g << 2);

    #pragma unroll 2
    for (int r = 0; r < 8; ++r) {               // 8 rounds x 128 cands
        const __fp16* apr = ap  + r * 2048;     // 128 cands * 16 halves
        const float*  sqr = sqp + r * 128;
        const uint32_t vb = vg4 + (uint32_t)(r << 7);
        uint32_t P[16];                          // pair-mins
        #pragma unroll
        for (int tt = 0; tt < 8; ++tt) {
            fp16x4 af = *(const fp16x4*)(apr + tt * 256);
            f32x4  sq = *(const f32x4*)(sqr + tt * 16);
            // acc[v] = |c|^2 + 128 - 2<c,q>, cands vb+tt*16+v (adjacent!)
            f32x4 acc = __builtin_amdgcn_mfma_f32_16x16x16f16(af, bfrag, sq, 0, 0, 0);
            const uint32_t it = vb + (uint32_t)(tt << 4);
            uint32_t k0 = (__float_as_uint(acc[0]) & 0xFFFFFC00u) | it;
            uint32_t k1 = (__float_as_uint(acc[1]) & 0xFFFFFC00u) | (it + 1u);
            uint32_t k2 = (__float_as_uint(acc[2]) & 0xFFFFFC00u) | (it + 2u);
            uint32_t k3 = (__float_as_uint(acc[3]) & 0xFFFFFC00u) | (it + 3u);
            P[tt * 2]     = umn(k0, k1);
            P[tt * 2 + 1] = umn(k2, k3);
        }
        sort16(P);
        #pragma unroll
        for (int i = 0; i < 16; ++i) A[i] = umn(A[i], P[15 - i]);
        clean16(A);
    }

    mergeg(A);  // A = sorted top-16 pair-mins over all 512 pairs (all 4 g-lanes equal)

    // ---- repair: partners of the 16 winning pairs; lane g handles winners 4g..4g+3 ----
    union H8 { f32x4 v[2]; fp16x2 h2[8]; };
    H8 qq;
    {
        const f32x4* qf = (const f32x4*)(sq16 + (size_t)(w * 16 + col) * 16);
        qq.v[0] = qf[0]; qq.v[1] = qf[1];
    }
    uint32_t B4[4];
    #pragma unroll
    for (int v = 0; v < 4; ++v) {
        const uint32_t av   = sel4(A, g, v);
        const uint32_t pidx = (av & 1023u) ^ 1u;   // pair partner
        H8 cc;
        const f32x4* cf = (const f32x4*)(sc + (size_t)pidx * 16);
        cc.v[0] = cf[0]; cc.v[1] = cf[1];
        float s = 0.0f;
        #pragma unroll
        for (int j = 0; j < 8; ++j) {
#if __has_builtin(__builtin_amdgcn_fdot2)
            s = __builtin_amdgcn_fdot2(cc.h2[j], qq.h2[j], s, false);
#else
            s = __builtin_fmaf((float)cc.h2[j][0], (float)qq.h2[j][0], s);
            s = __builtin_fmaf((float)cc.h2[j][1], (float)qq.h2[j][1], s);
#endif
        }
        const float val = s + ssq[pidx];           // |p|^2+128-2<p,q>
        B4[v] = (__float_as_uint(val) & 0xFFFFFC00u) | pidx;
    }
    // sort4
    CE(B4, 0, 1); CE(B4, 2, 3); CE(B4, 0, 2); CE(B4, 1, 3); CE(B4, 1, 2);
    // grow-merge partners across g (dup-free: winners only live in A):
    // xor16: sorted-4 + sorted-4 -> sorted-8
    uint32_t B8[8];
    {
        uint32_t Q[4];
        #pragma unroll
        for (int i = 0; i < 4; ++i) Q[i] = (uint32_t)__shfl_xor((int)B4[3 - i], 16, 64);
        #pragma unroll
        for (int i = 0; i < 4; ++i) { B8[i] = umn(B4[i], Q[i]); B8[i + 4] = umx(B4[i], Q[i]); }
        #pragma unroll
        for (int j = 2; j > 0; j >>= 1) {
            #pragma unroll
            for (int i = 0; i < 8; ++i) { int p = i ^ j; if (p > i) CE(B8, i, p); }
        }
    }
    // xor32: sorted-8 + sorted-8 -> sorted-16 (bitonic concat + clean)
    uint32_t S[16];
    #pragma unroll
    for (int i = 0; i < 8; ++i) S[i] = B8[i];
    #pragma unroll
    for (int i = 8; i < 16; ++i) S[i] = (uint32_t)__shfl_xor((int)B8[15 - i], 32, 64);
    clean16(S);
    // final keep-16 merge: A vs all 16 partner keys
    #pragma unroll
    for (int i = 0; i < 16; ++i) A[i] = umn(A[i], S[15 - i]);
    clean16(A);

    // ---- epilogue: lane (g,col) writes int4 #g of src and dst for its query ----
    const int base = seg * L_SEG;
    const int q    = base + qloc;
    int4 sv;
    sv.x = base + (int)(sel4(A, g, 0) & 1023u);
    sv.y = base + (int)(sel4(A, g, 1) & 1023u);
    sv.z = base + (int)(sel4(A, g, 2) & 1023u);
    sv.w = base + (int)(sel4(A, g, 3) & 1023u);
    ((int4*)out)[(size_t)q * 4 + g] = sv;
    ((int4*)out)[(size_t)M_PTS * 4 + (size_t)q * 4 + g] = make_int4(q, q, q, q);
}

extern "C" void kernel_launch(void* const* d_in, const int* in_sizes, int n_in,
                              void* d_out, int out_size, void* d_ws, size_t ws_size,
                              hipStream_t stream) {
    const float* x = (const float*)d_in[0];
    // d_in[1] = segs (int64, all 1024) — static per problem setup, unused.
    int* out = (int*)d_out;
    (void)d_ws; (void)ws_size;
    knn_v8_kernel<<<dim3(1024), dim3(256), 0, stream>>>(x, out);
}

// Round 9
// 86.450 us; speedup vs baseline: 1.1282x; 1.0021x over previous
//
#include <hip/hip_runtime.h>
#include <stdint.h>

// Segmented kNN graph: M=65536 pts, D=16, 64 segments x 1024 pts, K=16.
// Output: int32 src[M*16] then int32 dst[M*16].
//
// v9 = v8 with pair-min upgraded to EXACT quad-min pre-reduction.
// Evidence r5-r8: time tracks selection-network VALU count (occupancy and
// bank conflicts proven non-binding). One MFMA gives a lane 4 adjacent
// cands = one quad -> quadmin in 3 v_min. Top-16 of quad-mins covers the
// true top-16 (if x in top16, <=15 quads beat x's quad). Repair: 3 partners
// per winner (12 dots/lane via fdot2; winners one-per-quad -> partners
// disjoint across g-lanes). Main loop sorts 16 keys per 256 cands (v8: 128).
// Keys: f32 bits of (|c|^2+128-2<c,q>) | 10-bit idx (order-preserving).
// MFMA 16x16x16f16, C operand carries norms+bias.

#define L_SEG 1024
#define M_PTS 65536

typedef __fp16 fp16x2 __attribute__((ext_vector_type(2)));
typedef __fp16 fp16x4 __attribute__((ext_vector_type(4)));
typedef float  f32x4  __attribute__((ext_vector_type(4)));

__device__ __forceinline__ uint32_t umn(uint32_t a, uint32_t b) { return a < b ? a : b; }
__device__ __forceinline__ uint32_t umx(uint32_t a, uint32_t b) { return a > b ? a : b; }

#define CE(arr, i, p) { uint32_t lo = umn(arr[i], arr[p]); uint32_t hi = umx(arr[i], arr[p]); arr[i] = lo; arr[p] = hi; }

// bitonic clean of 16 (input bitonic, output sorted ascending): 32 CEs
__device__ __forceinline__ void clean16(uint32_t* A) {
    #pragma unroll
    for (int j = 8; j > 0; j >>= 1) {
        #pragma unroll
        for (int i = 0; i < 16; ++i) {
            int p = i ^ j;
            if (p > i) CE(A, i, p);
        }
    }
}

// Batcher odd-even mergesort-16, ascending (63 CEs)
__device__ __forceinline__ void sort16(uint32_t* B) {
    #pragma unroll
    for (int p = 1; p < 16; p <<= 1) {
        #pragma unroll
        for (int k = p; k >= 1; k >>= 1) {
            #pragma unroll
            for (int j = (k & (p - 1)); j + k < 16; j += 2 * k) {
                #pragma unroll
                for (int i = 0; i <= ((k - 1 < 15 - j - k) ? k - 1 : 15 - j - k); ++i) {
                    if ((i + j) / (2 * p) == (i + j + k) / (2 * p)) CE(B, i + j, i + j + k);
                }
            }
        }
    }
}

// merge sorted S (descending-taken) into sorted A, keep lowest 16
__device__ __forceinline__ void keep16(uint32_t* A, const uint32_t* S) {
    #pragma unroll
    for (int i = 0; i < 16; ++i) A[i] = umn(A[i], S[15 - i]);
    clean16(A);
}

// cross-lane merges over g (xor 16 then 32): disjoint contents per lane
__device__ __forceinline__ void mergeg(uint32_t* A) {
    #pragma unroll
    for (int m = 16; m <= 32; m <<= 1) {
        uint32_t P[16];
        #pragma unroll
        for (int i = 0; i < 16; ++i) P[i] = (uint32_t)__shfl_xor((int)A[15 - i], m, 64);
        #pragma unroll
        for (int i = 0; i < 16; ++i) A[i] = umn(A[i], P[i]);
        clean16(A);
    }
}

__device__ __forceinline__ uint32_t sel4(const uint32_t* A, int g, int v) {
    uint32_t t01 = (g & 1) ? A[4 + v]  : A[v];
    uint32_t t23 = (g & 1) ? A[12 + v] : A[8 + v];
    return (g & 2) ? t23 : t01;
}

__global__ __launch_bounds__(256, 4) void knn_v9_kernel(const float* __restrict__ x,
                                                        int* __restrict__ out) {
    __shared__ __attribute__((aligned(16))) __fp16 sc[L_SEG * 16];  // -2*c, [cand][dim], 32KB
    __shared__ __attribute__((aligned(16))) float  ssq[L_SEG];      // |c|^2 + 128 (f32)
    __shared__ __attribute__((aligned(16))) __fp16 sq16[64 * 16];   // block's queries, f16

    const int tid = threadIdx.x;
    const int b   = blockIdx.x;
    const int seg = (b & 7) * 8 + (b >> 7);  // XCD swizzle, bijective
    const int qp  = (b >> 3) & 15;
    const float* xseg = x + (size_t)seg * (L_SEG * 16);
    const f32x4* gx4  = (const f32x4*)xseg;

    // ---- stage coords * -2 as f16, [cand][dim] layout ----
    {
        fp16x4* scv = (fp16x4*)sc;
        #pragma unroll
        for (int i = 0; i < 16; ++i) {
            f32x4 v = gx4[tid + 256 * i];
            union { fp16x2 h2[2]; fp16x4 h4; } u;
            u.h2[0] = __builtin_amdgcn_cvt_pkrtz(-2.0f * v[0], -2.0f * v[1]);
            u.h2[1] = __builtin_amdgcn_cvt_pkrtz(-2.0f * v[2], -2.0f * v[3]);
            scv[tid + 256 * i] = u.h4;
        }
    }
    // ---- stage biased norms (f32 from global) ----
    {
        const int c0 = tid << 2;
        #pragma unroll
        for (int c = 0; c < 4; ++c) {
            float s = 128.0f;
            #pragma unroll
            for (int d = 0; d < 4; ++d) {
                f32x4 v = gx4[(c0 + c) * 4 + d];
                s = __builtin_fmaf(v[0], v[0], s);
                s = __builtin_fmaf(v[1], v[1], s);
                s = __builtin_fmaf(v[2], v[2], s);
                s = __builtin_fmaf(v[3], v[3], s);
            }
            ssq[c0 + c] = s;
        }
    }
    // ---- stage this block's 64 queries (unscaled f16) ----
    if (tid < 64) {
        const f32x4* qg = gx4 + (size_t)(qp * 64 + tid) * 4;
        fp16x4* dst = (fp16x4*)(sq16 + (size_t)tid * 16);
        #pragma unroll
        for (int d = 0; d < 4; ++d) {
            f32x4 v = qg[d];
            union { fp16x2 h2[2]; fp16x4 h4; } u;
            u.h2[0] = __builtin_amdgcn_cvt_pkrtz(v[0], v[1]);
            u.h2[1] = __builtin_amdgcn_cvt_pkrtz(v[2], v[3]);
            dst[d] = u.h4;
        }
    }
    __syncthreads();

    const int lane = tid & 63;
    const int w    = tid >> 6;
    const int g    = lane >> 4;   // lane owns cands (tile base + 4g..4g+3)
    const int col  = lane & 15;   // query column
    const int qloc = qp * 64 + w * 16 + col;

    const fp16x4 bfrag = *(const fp16x4*)(sq16 + (size_t)(w * 16 + col) * 16 + g * 4);

    uint32_t A[16];
    #pragma unroll
    for (int i = 0; i < 16; ++i) A[i] = 0xFFFFFFFFu;

    const __fp16* ap  = sc + (size_t)col * 16 + g * 4;   // + cand*16 halves
    const float*  sqp = ssq + g * 4;
    const uint32_t vg4 = (uint32_t)(g << 2);

    #pragma unroll 2
    for (int it = 0; it < 4; ++it) {             // 4 iters x 256 cands
        uint32_t P[16];                          // one quad-min per MFMA tile
        #pragma unroll
        for (int t = 0; t < 16; ++t) {
            const int cb = it * 256 + t * 16;    // tile base
            fp16x4 af = *(const fp16x4*)(ap + (size_t)cb * 16);
            f32x4  sq = *(const f32x4*)(sqp + cb);
            // acc[v] = |c|^2 + 128 - 2<c,q>, cand = cb + 4g + v (one quad!)
            f32x4 acc = __builtin_amdgcn_mfma_f32_16x16x16f16(af, bfrag, sq, 0, 0, 0);
            const uint32_t ib = (uint32_t)cb + vg4;
            uint32_t k0 = (__float_as_uint(acc[0]) & 0xFFFFFC00u) | ib;
            uint32_t k1 = (__float_as_uint(acc[1]) & 0xFFFFFC00u) | (ib + 1u);
            uint32_t k2 = (__float_as_uint(acc[2]) & 0xFFFFFC00u) | (ib + 2u);
            uint32_t k3 = (__float_as_uint(acc[3]) & 0xFFFFFC00u) | (ib + 3u);
            P[t] = umn(umn(k0, k1), umn(k2, k3));
        }
        sort16(P);
        keep16(A, P);
    }

    mergeg(A);  // all 4 g-lanes: identical sorted top-16 quad-mins of 256 quads

    // ---- repair: 3 quad-partners per winner; lane g handles winners 4g..4g+3 ----
    union H8 { f32x4 v[2]; fp16x2 h2[8]; };
    H8 qq;
    {
        const f32x4* qf = (const f32x4*)(sq16 + (size_t)(w * 16 + col) * 16);
        qq.v[0] = qf[0]; qq.v[1] = qf[1];
    }
    uint32_t R[16];
    #pragma unroll
    for (int v = 0; v < 4; ++v) {
        const uint32_t win = sel4(A, g, v);
        const uint32_t wi  = win & 1023u;
        const uint32_t qb  = wi & ~3u;
        const uint32_t wo  = wi & 3u;
        #pragma unroll
        for (int k = 0; k < 3; ++k) {
            const uint32_t o    = (uint32_t)k + (((uint32_t)k >= wo) ? 1u : 0u);
            const uint32_t pidx = qb + o;
            H8 cc;
            const f32x4* cf = (const f32x4*)(sc + (size_t)pidx * 16);  // -2*c
            cc.v[0] = cf[0]; cc.v[1] = cf[1];
            float s = 0.0f;
            #pragma unroll
            for (int j = 0; j < 8; ++j) {
#if __has_builtin(__builtin_amdgcn_fdot2)
                s = __builtin_amdgcn_fdot2(cc.h2[j], qq.h2[j], s, false);
#else
                s = __builtin_fmaf((float)cc.h2[j][0], (float)qq.h2[j][0], s);
                s = __builtin_fmaf((float)cc.h2[j][1], (float)qq.h2[j][1], s);
#endif
            }
            const float val = s + ssq[pidx];     // |p|^2 + 128 - 2<p,q>
            R[v * 3 + k] = (__float_as_uint(val) & 0xFFFFFC00u) | pidx;
        }
    }
    #pragma unroll
    for (int i = 12; i < 16; ++i) R[i] = 0xFFFFFFFFu;
    sort16(R);
    mergeg(R);       // 48 partners across g-lanes -> lowest 16, all lanes equal
    keep16(A, R);    // final exact top-16 = keep-16 of winners ∪ partners

    // ---- epilogue: lane (g,col) writes int4 #g of src and dst for its query ----
    const int base = seg * L_SEG;
    const int q    = base + qloc;
    int4 sv;
    sv.x = base + (int)(sel4(A, g, 0) & 1023u);
    sv.y = base + (int)(sel4(A, g, 1) & 1023u);
    sv.z = base + (int)(sel4(A, g, 2) & 1023u);
    sv.w = base + (int)(sel4(A, g, 3) & 1023u);
    ((int4*)out)[(size_t)q * 4 + g] = sv;
    ((int4*)out)[(size_t)M_PTS * 4 + (size_t)q * 4 + g] = make_int4(q, q, q, q);
}

extern "C" void kernel_launch(void* const* d_in, const int* in_sizes, int n_in,
                              void* d_out, int out_size, void* d_ws, size_t ws_size,
                              hipStream_t stream) {
    const float* x = (const float*)d_in[0];
    // d_in[1] = segs (int64, all 1024) — static per problem setup, unused.
    int* out = (int*)d_out;
    (void)d_ws; (void)ws_size;
    knn_v9_kernel<<<dim3(1024), dim3(256), 0, stream>>>(x, out);
}